// Round 8
// baseline (416.678 us; speedup 1.0000x reference)
//
#include <hip/hip_runtime.h>
#include <hip/hip_bf16.h>
#include <cstdint>
#include <cstddef>

#define DEVI __device__ __forceinline__

typedef unsigned short u16;
using frag_ab = __attribute__((ext_vector_type(8))) short;   // 8 bf16 (4 VGPRs)
using f32x4   = __attribute__((ext_vector_type(4))) float;   // mfma acc
using u32x4   = __attribute__((ext_vector_type(4))) unsigned int;  // 16B nontemporal store

constexpr int HW = 16384;   // 128*128 spatial
constexpr int NC = 256;     // channels (Cin = Cout = 256)

DEVI u16 bf16bits(float f) {
    union { float f; uint32_t u; } cv; cv.f = f;
    uint32_t u = cv.u;
    u += 0x7fffu + ((u >> 16) & 1u);   // RNE
    return (u16)(u >> 16);
}

DEVI void gload16(const void* g, void* l) {
    __builtin_amdgcn_global_load_lds(
        (const __attribute__((address_space(1))) uint32_t*)g,
        (__attribute__((address_space(3))) uint32_t*)l, 16, 0, 0);
}

// LDS slab: [row][64B]; 16B slot s at phys slot s ^ (row&3) ^ ((row>>2)&3).
// Staging fetches pre-swizzled global slot (m173); frag reads use matching phys.
DEVI frag_ab read_frag(const u16* slab, int row, int l4) {
    const int phys = (l4 ^ row ^ (row >> 2)) & 3;
    return *(const frag_ab*)((const char*)slab + row * 64 + phys * 16);
}

// ---------------- pass 1: x partial stats + transpose to xt[b][p][c] bf16 ----------------
// partials ps/pq[b][pblk][c]: full-sector float4 stores, fold reduces coalesced over pblk
__global__ __launch_bounds__(256) void transpose_stats_kernel(
    const float* __restrict__ x, u16* __restrict__ xt,
    float* __restrict__ ps, float* __restrict__ pq)
{
    constexpr int PADW = 68;                       // row pitch in u16 (136B)
    __shared__ __align__(16) u16 tile[64 * PADW];  // [px][ch]
    const int b = blockIdx.z, c0 = blockIdx.y * 64, p0 = blockIdx.x * 64;
    const int pblk = blockIdx.x;                   // 0..255
    const int t = threadIdx.x;
    const int lane = t & 63, w = t >> 6;
    const int pq_ = lane & 15, cq = lane >> 4;
    const int quad = w * 4 + cq;                   // ch-quad 0..15
    const float* xb = x + ((size_t)b * NC + c0) * HW + p0;

    float va[4][4];                                // [j=ch][i=px]
    float aS[4], aQ[4];
    #pragma unroll
    for (int j = 0; j < 4; ++j) {
        const float4 v = *(const float4*)(xb + (size_t)(quad * 4 + j) * HW + pq_ * 4);
        va[j][0] = v.x; va[j][1] = v.y; va[j][2] = v.z; va[j][3] = v.w;
        float s1 = v.x + v.y + v.z + v.w;
        float s2 = v.x*v.x + v.y*v.y + v.z*v.z + v.w*v.w;
        #pragma unroll
        for (int d = 1; d < 16; d <<= 1) {
            s1 += __shfl_xor(s1, d, 64);
            s2 += __shfl_xor(s2, d, 64);
        }
        aS[j] = s1; aQ[j] = s2;
    }
    if (pq_ == 0) {                                // lanes 0,16,32,48: one 16B store each
        const float4 vs = {aS[0], aS[1], aS[2], aS[3]};
        const float4 vq = {aQ[0], aQ[1], aQ[2], aQ[3]};
        *(float4*)&ps[((size_t)b * 256 + pblk) * NC + c0 + quad * 4] = vs;
        *(float4*)&pq[((size_t)b * 256 + pblk) * NC + c0 + quad * 4] = vq;
    }
    #pragma unroll
    for (int i = 0; i < 4; ++i) {
        alignas(8) u16 pk[4];
        #pragma unroll
        for (int j = 0; j < 4; ++j) pk[j] = bf16bits(va[j][i]);
        *(uint2*)&tile[(pq_ * 4 + i) * PADW + quad * 4] = *(const uint2*)pk;
    }
    __syncthreads();
    const int pl = t >> 2, q = t & 3;
    u16* dst = xt + ((size_t)b * HW + p0 + pl) * NC + c0;
    #pragma unroll
    for (int s = 0; s < 2; ++s) {
        const int ch8 = q + s * 4;
        const uint2 lo = *(const uint2*)&tile[pl * PADW + ch8 * 8];
        const uint2 hi = *(const uint2*)&tile[pl * PADW + ch8 * 8 + 4];
        const u32x4 o4 = {lo.x, lo.y, hi.x, hi.y};
        __builtin_nontemporal_store(o4, (u32x4*)(dst + ch8 * 8));
    }
}

// ---------------- fold: reduce partials[b][256][c] -> mu/rs, fold IN into weights/bias ----------------
__global__ __launch_bounds__(256) void fold_kernel(
    const float* __restrict__ w, const float* __restrict__ bias,
    const float* __restrict__ ps, const float* __restrict__ pq,
    u16* __restrict__ we, float* __restrict__ be)
{
    const int b = blockIdx.y, oc = blockIdx.x * 64;
    __shared__ float mu[NC], rs[NC];
    __shared__ __align__(16) float wt[64 * NC];
    const int t = threadIdx.x;
    {
        float s1 = 0.f, s2 = 0.f;
        const float* pp = ps + (size_t)b * 256 * NC + t;    // [i][t], coalesced across threads
        const float* qq = pq + (size_t)b * 256 * NC + t;
        for (int i = 0; i < 256; ++i) {
            s1 += pp[(size_t)i * NC];
            s2 += qq[(size_t)i * NC];
        }
        const float m = s1 * (1.0f / HW);
        mu[t] = m;
        rs[t] = rsqrtf(s2 * (1.0f / HW) - m * m + 1e-5f);
    }
    #pragma unroll
    for (int i = 0; i < 16; ++i)
        *(float4*)&wt[i*1024 + t*4] = *(const float4*)&w[(size_t)oc*NC + i*1024 + t*4];
    __syncthreads();
    const int o = oc + (t >> 2), q = t & 3;
    const float* wrow = &wt[(t >> 2) * NC];
    u16* werow = we + ((size_t)b * NC + o) * NC;
    float bacc = 0.f;
    for (int cc = 0; cc < 8; ++cc) {
        alignas(16) u16 pk[8];
        #pragma unroll
        for (int jj = 0; jj < 8; ++jj) {
            const int c = q*64 + cc*8 + jj;
            const float wv = wrow[c];
            bacc -= wv * mu[c] * rs[c];
            pk[jj] = bf16bits(wv * rs[c]);
        }
        *(uint4*)(werow + q*64 + cc*8) = *(const uint4*)pk;
    }
    bacc += __shfl_xor(bacc, 1, 64);
    bacc += __shfl_xor(bacc, 2, 64);
    if (q == 0) be[b*NC + o] = bias[o] + bacc;
}

// ---------------- fused GEMM: pixels-in-LDS (full K burst), weights global->VGPR ----------------
// 64 px x 256 outs per block, 4 waves. Prologue bursts the full-K pixel strip (32 KB) once;
// ONE barrier total. k-loop: W fragments loaded straight from global (L2-resident, 128 KB/b)
// into VGPRs, double-buffered one k-step ahead; zero k-loop barriers.
// STAGE1 -> ht[b][p][o] bf16 + h partials [b][pblk][o]; STAGE2 -> out[b][o][p] fp32.
template<int STAGE>
__global__ __launch_bounds__(256, 3) void gemm_kernel(
    const u16* __restrict__ pixM,   // [B*HW][NC] (xt or ht)
    const u16* __restrict__ wMat,   // [B][NC][NC] folded weights
    const float* __restrict__ biasE,// [B][NC]
    u16* __restrict__ outB,         // stage1: ht
    float* __restrict__ outF,       // stage2: out
    float* __restrict__ hps, float* __restrict__ hpq)
{
    __shared__ __align__(16) u16 ldsP[8 * 64 * 32];   // 32 KB: 8 k-slices of [64 rows][32 k]

    const int b = blockIdx.y, pblk = blockIdx.x;
    const int p0 = pblk * 64;
    const int tid = threadIdx.x;
    const int lane = tid & 63, wid = tid >> 6;        // 4 waves; wave owns outs [wid*64, +64)
    const int l15 = lane & 15, l4 = lane >> 4;

    const u16* gP = pixM + ((size_t)b * HW + p0) * NC;
    const u16* gW = wMat + (size_t)b * NC * NC;

    const int rin  = lane >> 2;
    const int prow = wid * 16 + rin;                  // pixel row 0..63
    const int psl  = ((lane & 3) ^ prow ^ (prow >> 2)) & 3;

    // ---- prologue burst: all 8 pixel k-slices (8 gload16/thread in flight)
    #pragma unroll
    for (int ks = 0; ks < 8; ++ks)
        gload16(gP + (size_t)prow * NC + ks * 32 + psl * 8,
                (char*)ldsP + ks * 4096 + wid * 1024);

    // W frag base: frag f at k-step ks reads row (wid*64 + 16f + l15), elems ks*32 + l4*8
    const u16* wbase = gW + (size_t)(wid * 64 + l15) * NC + l4 * 8;

    f32x4 acc[4][4];
    #pragma unroll
    for (int i = 0; i < 4; ++i)
        #pragma unroll
        for (int j = 0; j < 4; ++j)
            acc[i][j] = (f32x4){0.f, 0.f, 0.f, 0.f};

    frag_ab wf[2][4];
    #pragma unroll
    for (int f = 0; f < 4; ++f)
        wf[0][f] = *(const frag_ab*)(wbase + (size_t)f * 16 * NC);

    asm volatile("s_waitcnt vmcnt(0)" ::: "memory");  // pixel slab (over-waits wf[0]: harmless)
    __builtin_amdgcn_s_barrier();                     // the only barrier in this kernel

    #pragma unroll
    for (int ks = 0; ks < 8; ++ks) {
        const int cur = ks & 1;
        if (ks < 7) {                                 // prefetch next W frags into other buffer
            #pragma unroll
            for (int f = 0; f < 4; ++f)
                wf[cur ^ 1][f] = *(const frag_ab*)(wbase + (size_t)f * 16 * NC + (ks + 1) * 32);
        }
        const u16* pslab = ldsP + ks * 2048;          // 4096 B slice
        frag_ab pf[4];
        #pragma unroll
        for (int f = 0; f < 4; ++f)
            pf[f] = read_frag(pslab, 16 * f + l15, l4);

        #pragma unroll
        for (int ni = 0; ni < 4; ++ni)
            #pragma unroll
            for (int mi = 0; mi < 4; ++mi) {
                if constexpr (STAGE == 1)
                    acc[mi][ni] = __builtin_amdgcn_mfma_f32_16x16x32_bf16(pf[mi], wf[cur][ni], acc[mi][ni], 0, 0, 0);
                else
                    acc[mi][ni] = __builtin_amdgcn_mfma_f32_16x16x32_bf16(wf[cur][mi], pf[ni], acc[mi][ni], 0, 0, 0);
            }
    }

    if constexpr (STAGE == 1) {
        // acc rows = pixels (16mi + l4*4 + r), cols = outs (wid*64 + 16ni + l15)
        u16* htp = outB + ((size_t)b * HW + p0) * NC + wid * 64;
        float s1[4] = {0.f,0.f,0.f,0.f}, s2[4] = {0.f,0.f,0.f,0.f};
        #pragma unroll
        for (int ni = 0; ni < 4; ++ni) {
            const float bn = biasE[b*NC + wid*64 + 16*ni + l15];
            #pragma unroll
            for (int mi = 0; mi < 4; ++mi) {
                #pragma unroll
                for (int r = 0; r < 4; ++r) {
                    const float v = fmaxf(acc[mi][ni][r] + bn, 0.f);
                    s1[ni] += v; s2[ni] += v * v;
                    __builtin_nontemporal_store(bf16bits(v),
                        htp + (size_t)(16*mi + l4*4 + r) * NC + 16*ni + l15);
                }
            }
        }
        #pragma unroll
        for (int ni = 0; ni < 4; ++ni) {
            float a1 = s1[ni], a2 = s2[ni];
            a1 += __shfl_xor(a1, 16, 64); a1 += __shfl_xor(a1, 32, 64);
            a2 += __shfl_xor(a2, 16, 64); a2 += __shfl_xor(a2, 32, 64);
            if (l4 == 0) {                             // 16 lanes x 4B = full 64B sector
                const int col = wid*64 + 16*ni + l15;
                hps[((size_t)b * 256 + pblk) * NC + col] = a1;
                hpq[((size_t)b * 256 + pblk) * NC + col] = a2;
            }
        }
    } else {
        // acc rows = outs (wid*64 + 16mi + l4*4 + r), cols = pixels -> native NCHW
        float* op = outF + ((size_t)b * NC + wid * 64) * HW + p0;
        #pragma unroll
        for (int mi = 0; mi < 4; ++mi) {
            #pragma unroll
            for (int r = 0; r < 4; ++r) {
                const int orow = 16*mi + l4*4 + r;
                const float bm = biasE[b*NC + wid*64 + orow];
                #pragma unroll
                for (int ni = 0; ni < 4; ++ni)
                    __builtin_nontemporal_store(fmaxf(acc[mi][ni][r] + bm, 0.f),
                        op + (size_t)orow * HW + 16*ni + l15);
            }
        }
    }
}

extern "C" void kernel_launch(void* const* d_in, const int* in_sizes, int n_in,
                              void* d_out, int out_size, void* d_ws, size_t ws_size,
                              hipStream_t stream)
{
    (void)in_sizes; (void)n_in; (void)out_size;
    const float* x  = (const float*)d_in[0];
    const float* w1 = (const float*)d_in[1];
    const float* b1 = (const float*)d_in[2];
    const float* w2 = (const float*)d_in[3];
    const float* b2 = (const float*)d_in[4];
    float* out = (float*)d_out;

    // scratch carved out of d_out (268 MB): dead before gemm<2> overwrites it
    char* od = (char*)d_out;
    u16*   xt  = (u16*)od;                        // 134,217,728 B
    float* xps = (float*)(od + 134217728);        //   4,194,304 (16*256*256 f32)
    float* xpq = (float*)(od + 138412032);        //   4,194,304
    float* hps = (float*)(od + 142606336);        //   4,194,304
    float* hpq = (float*)(od + 146800640);        //   4,194,304

    char* ws = (char*)d_ws;
    const size_t NEED = 138444800;
    if (ws_size < NEED) return;
    u16*   ht  = (u16*)(ws);                      // 134,217,728
    u16*   w1e = (u16*)(ws + 134217728);          //   2,097,152
    u16*   w2e = (u16*)(ws + 136314880);          //   2,097,152
    float* b1e = (float*)(ws + 138412032);        //      16,384
    float* b2e = (float*)(ws + 138428416);        //      16,384

    transpose_stats_kernel<<<dim3(HW/64, NC/64, 16), 256, 0, stream>>>(x, xt, xps, xpq);
    fold_kernel<<<dim3(4, 16), 256, 0, stream>>>(w1, b1, xps, xpq, w1e, b1e);
    gemm_kernel<1><<<dim3(HW/64, 16), 256, 0, stream>>>(xt, w1e, b1e, ht, nullptr, hps, hpq);
    fold_kernel<<<dim3(4, 16), 256, 0, stream>>>(w2, b2, hps, hpq, w2e, b2e);
    gemm_kernel<2><<<dim3(HW/64, 16), 256, 0, stream>>>(ht, w2e, b2e, nullptr, out, nullptr, nullptr);
}

// Round 9
// 337.835 us; speedup vs baseline: 1.2334x; 1.2334x over previous
//
#include <hip/hip_runtime.h>
#include <hip/hip_bf16.h>
#include <cstdint>
#include <cstddef>

#define DEVI __device__ __forceinline__

typedef unsigned short u16;
using frag_ab = __attribute__((ext_vector_type(8))) short;   // 8 bf16 (4 VGPRs)
using f32x4   = __attribute__((ext_vector_type(4))) float;   // mfma acc

constexpr int HW = 16384;   // 128*128 spatial
constexpr int NC = 256;     // channels (Cin = Cout = 256)

DEVI u16 bf16bits(float f) {
    union { float f; uint32_t u; } cv; cv.f = f;
    uint32_t u = cv.u;
    u += 0x7fffu + ((u >> 16) & 1u);   // RNE
    return (u16)(u >> 16);
}

DEVI void gload16(const void* g, void* l) {
    __builtin_amdgcn_global_load_lds(
        (const __attribute__((address_space(1))) uint32_t*)g,
        (__attribute__((address_space(3))) uint32_t*)l, 16, 0, 0);
}

// LDS slab: [row][64B]; 16B slot s at phys slot s ^ (row&3) ^ ((row>>2)&3).
// Staging fetches pre-swizzled global slot (m173); frag reads use matching phys.
DEVI frag_ab read_frag(const u16* slab, int row, int l4) {
    const int phys = (l4 ^ row ^ (row >> 2)) & 3;
    return *(const frag_ab*)((const char*)slab + row * 64 + phys * 16);
}

// ---------------- pass 1: x partial stats + transpose to xt[b][p][c] bf16 ----------------
// partials ps/pq[b][pblk][c]: full-sector float4 stores, fold reduces coalesced over pblk
__global__ __launch_bounds__(256) void transpose_stats_kernel(
    const float* __restrict__ x, u16* __restrict__ xt,
    float* __restrict__ ps, float* __restrict__ pq)
{
    constexpr int PADW = 68;                       // row pitch in u16 (136B)
    __shared__ __align__(16) u16 tile[64 * PADW];  // [px][ch]
    const int b = blockIdx.z, c0 = blockIdx.y * 64, p0 = blockIdx.x * 64;
    const int pblk = blockIdx.x;                   // 0..255
    const int t = threadIdx.x;
    const int lane = t & 63, w = t >> 6;
    const int pq_ = lane & 15, cq = lane >> 4;
    const int quad = w * 4 + cq;                   // ch-quad 0..15
    const float* xb = x + ((size_t)b * NC + c0) * HW + p0;

    float va[4][4];                                // [j=ch][i=px]
    float aS[4], aQ[4];
    #pragma unroll
    for (int j = 0; j < 4; ++j) {
        const float4 v = *(const float4*)(xb + (size_t)(quad * 4 + j) * HW + pq_ * 4);
        va[j][0] = v.x; va[j][1] = v.y; va[j][2] = v.z; va[j][3] = v.w;
        float s1 = v.x + v.y + v.z + v.w;
        float s2 = v.x*v.x + v.y*v.y + v.z*v.z + v.w*v.w;
        #pragma unroll
        for (int d = 1; d < 16; d <<= 1) {
            s1 += __shfl_xor(s1, d, 64);
            s2 += __shfl_xor(s2, d, 64);
        }
        aS[j] = s1; aQ[j] = s2;
    }
    if (pq_ == 0) {                                // lanes 0,16,32,48: one 16B store each
        const float4 vs = {aS[0], aS[1], aS[2], aS[3]};
        const float4 vq = {aQ[0], aQ[1], aQ[2], aQ[3]};
        *(float4*)&ps[((size_t)b * 256 + pblk) * NC + c0 + quad * 4] = vs;
        *(float4*)&pq[((size_t)b * 256 + pblk) * NC + c0 + quad * 4] = vq;
    }
    #pragma unroll
    for (int i = 0; i < 4; ++i) {
        alignas(8) u16 pk[4];
        #pragma unroll
        for (int j = 0; j < 4; ++j) pk[j] = bf16bits(va[j][i]);
        *(uint2*)&tile[(pq_ * 4 + i) * PADW + quad * 4] = *(const uint2*)pk;
    }
    __syncthreads();
    const int pl = t >> 2, q = t & 3;
    u16* dst = xt + ((size_t)b * HW + p0 + pl) * NC + c0;
    #pragma unroll
    for (int s = 0; s < 2; ++s) {
        const int ch8 = q + s * 4;
        const uint2 lo = *(const uint2*)&tile[pl * PADW + ch8 * 8];
        const uint2 hi = *(const uint2*)&tile[pl * PADW + ch8 * 8 + 4];
        const uint4 o4 = {lo.x, lo.y, hi.x, hi.y};
        *(uint4*)(dst + ch8 * 8) = o4;
    }
}

// ---------------- fold: reduce partials[b][256][c] -> mu/rs, fold IN into weights/bias ----------------
__global__ __launch_bounds__(256) void fold_kernel(
    const float* __restrict__ w, const float* __restrict__ bias,
    const float* __restrict__ ps, const float* __restrict__ pq,
    u16* __restrict__ we, float* __restrict__ be)
{
    const int b = blockIdx.y, oc = blockIdx.x * 64;
    __shared__ float mu[NC], rs[NC];
    __shared__ __align__(16) float wt[64 * NC];
    const int t = threadIdx.x;
    {
        float s1 = 0.f, s2 = 0.f;
        const float* pp = ps + (size_t)b * 256 * NC + t;    // [i][t], coalesced across threads
        const float* qq = pq + (size_t)b * 256 * NC + t;
        for (int i = 0; i < 256; ++i) {
            s1 += pp[(size_t)i * NC];
            s2 += qq[(size_t)i * NC];
        }
        const float m = s1 * (1.0f / HW);
        mu[t] = m;
        rs[t] = rsqrtf(s2 * (1.0f / HW) - m * m + 1e-5f);
    }
    #pragma unroll
    for (int i = 0; i < 16; ++i)
        *(float4*)&wt[i*1024 + t*4] = *(const float4*)&w[(size_t)oc*NC + i*1024 + t*4];
    __syncthreads();
    const int o = oc + (t >> 2), q = t & 3;
    const float* wrow = &wt[(t >> 2) * NC];
    u16* werow = we + ((size_t)b * NC + o) * NC;
    float bacc = 0.f;
    for (int cc = 0; cc < 8; ++cc) {
        alignas(16) u16 pk[8];
        #pragma unroll
        for (int jj = 0; jj < 8; ++jj) {
            const int c = q*64 + cc*8 + jj;
            const float wv = wrow[c];
            bacc -= wv * mu[c] * rs[c];
            pk[jj] = bf16bits(wv * rs[c]);
        }
        *(uint4*)(werow + q*64 + cc*8) = *(const uint4*)pk;
    }
    bacc += __shfl_xor(bacc, 1, 64);
    bacc += __shfl_xor(bacc, 2, 64);
    if (q == 0) be[b*NC + o] = bias[o] + bacc;
}

// ---------------- fused GEMM: P full-K burst in LDS + 3-slab counted-vmcnt W pipeline ----------------
// 64 px x 256 outs per block, 4 waves. Each wave stages AND reads only its own W quarter
// (rows wid*64..+64) -> no k-loop barriers; the single barrier covers the shared P strip.
// W slabs triple-buffered; steady-state wait = vmcnt(4) (own next slab stays in flight).
// Operand order per stage chosen so the reg-indexed acc dim matches the output's
// contiguous dim -> 16 wide stores/thread (uint2 / float4) instead of 64 scalar.
// STAGE1 -> ht[b][p][o] bf16 + h partials [b][pblk][o]; STAGE2 -> out[b][o][p] fp32.
template<int STAGE>
__global__ __launch_bounds__(256, 2) void gemm_kernel(
    const u16* __restrict__ pixM,   // [B*HW][NC] (xt or ht)
    const u16* __restrict__ wMat,   // [B][NC][NC] folded weights
    const float* __restrict__ biasE,// [B][NC]
    u16* __restrict__ outB,         // stage1: ht
    float* __restrict__ outF,       // stage2: out
    float* __restrict__ hps, float* __restrict__ hpq)
{
    __shared__ __align__(16) u16 ldsP[8 * 64 * 32];   // 32 KB: 8 k-slices of [64 rows][32 k]
    __shared__ __align__(16) u16 ldsW[3][256 * 32];   // 3 x 16 KB W slabs (per-wave quarters)

    const int b = blockIdx.y, pblk = blockIdx.x;
    const int p0 = pblk * 64;
    const int tid = threadIdx.x;
    const int lane = tid & 63, wid = tid >> 6;        // 4 waves; wave owns outs [wid*64, +64)
    const int l15 = lane & 15, l4 = lane >> 4;

    const u16* gP = pixM + ((size_t)b * HW + p0) * NC;
    const u16* gW = wMat + (size_t)b * NC * NC;

    const int rin  = lane >> 2;
    const int prow = wid * 16 + rin;                  // pixel row 0..63
    const int psl  = ((lane & 3) ^ prow ^ (prow >> 2)) & 3;
    int wrowq[4], wslq[4];
    #pragma unroll
    for (int q = 0; q < 4; ++q) {
        wrowq[q] = wid * 64 + q * 16 + rin;           // own W rows
        wslq[q]  = ((lane & 3) ^ wrowq[q] ^ (wrowq[q] >> 2)) & 3;
    }

    auto stageW = [&](int ks, int buf) {
        const int k0 = ks * 32;
        #pragma unroll
        for (int q = 0; q < 4; ++q)
            gload16(gW + (size_t)wrowq[q] * NC + k0 + wslq[q] * 8,
                    (char*)ldsW[buf] + (wid * 4 + q) * 1024);
    };

    // ---- prologue: full pixel strip + first two W slabs (16 loads/thread in flight)
    #pragma unroll
    for (int ks = 0; ks < 8; ++ks)
        gload16(gP + (size_t)prow * NC + ks * 32 + psl * 8,
                (char*)ldsP + ks * 4096 + wid * 1024);
    stageW(0, 0);
    stageW(1, 1);

    f32x4 acc[4][4];
    #pragma unroll
    for (int i = 0; i < 4; ++i)
        #pragma unroll
        for (int j = 0; j < 4; ++j)
            acc[i][j] = (f32x4){0.f, 0.f, 0.f, 0.f};

    asm volatile("s_waitcnt vmcnt(4)" ::: "memory");  // P + W0 landed; W1 in flight
    __builtin_amdgcn_s_barrier();                     // the only barrier: P visible to all waves

    #pragma unroll
    for (int ks = 0; ks < 8; ++ks) {
        if (ks >= 1) {
            if (ks < 7) asm volatile("s_waitcnt vmcnt(4)" ::: "memory");  // own W_ks ready
            else        asm volatile("s_waitcnt vmcnt(0)" ::: "memory");
        }
        const u16* wslab = ldsW[ks % 3];
        const u16* pslab = ldsP + ks * 2048;          // 4096 B slice

        frag_ab a[4], bfr[4];
        if constexpr (STAGE == 1) {                   // A = W (reg dim = out), B = P
            #pragma unroll
            for (int f = 0; f < 4; ++f) a[f]   = read_frag(wslab, wid * 64 + 16*f + l15, l4);
            #pragma unroll
            for (int f = 0; f < 4; ++f) bfr[f] = read_frag(pslab, 16*f + l15, l4);
        } else {                                      // A = P (reg dim = px), B = W
            #pragma unroll
            for (int f = 0; f < 4; ++f) a[f]   = read_frag(pslab, 16*f + l15, l4);
            #pragma unroll
            for (int f = 0; f < 4; ++f) bfr[f] = read_frag(wslab, wid * 64 + 16*f + l15, l4);
        }

        #pragma unroll
        for (int ni = 0; ni < 4; ++ni)
            #pragma unroll
            for (int mi = 0; mi < 4; ++mi)
                acc[mi][ni] = __builtin_amdgcn_mfma_f32_16x16x32_bf16(a[mi], bfr[ni], acc[mi][ni], 0, 0, 0);

        if (ks + 2 < 8) {                             // re-stage W_{ks+2} over slab read at ks-1
            asm volatile("s_waitcnt lgkmcnt(0)" ::: "memory");  // its ds_reads fully drained
            stageW(ks + 2, (ks + 2) % 3);
        }
    }

    if constexpr (STAGE == 1) {
        // acc: reg dim = out (wid*64 + 16mi + l4*4 + r), lane dim = px (16ni + l15)
        u16* htbase = outB + ((size_t)b * HW + p0) * NC + wid * 64;
        float4 vb[4];
        #pragma unroll
        for (int mi = 0; mi < 4; ++mi)
            vb[mi] = *(const float4*)&biasE[b*NC + wid*64 + 16*mi + l4*4];
        float s1v[4][4], s2v[4][4];
        #pragma unroll
        for (int mi = 0; mi < 4; ++mi)
            #pragma unroll
            for (int r = 0; r < 4; ++r) { s1v[mi][r] = 0.f; s2v[mi][r] = 0.f; }

        #pragma unroll
        for (int ni = 0; ni < 4; ++ni) {
            u16* rowp = htbase + (size_t)(16*ni + l15) * NC;
            #pragma unroll
            for (int mi = 0; mi < 4; ++mi) {
                alignas(8) u16 pk[4];
                const float bx[4] = {vb[mi].x, vb[mi].y, vb[mi].z, vb[mi].w};
                #pragma unroll
                for (int r = 0; r < 4; ++r) {
                    const float v = fmaxf(acc[mi][ni][r] + bx[r], 0.f);
                    s1v[mi][r] += v; s2v[mi][r] += v * v;
                    pk[r] = bf16bits(v);
                }
                *(uint2*)&rowp[16*mi + l4*4] = *(const uint2*)pk;   // 8B store, 4 consecutive o
            }
        }
        // reduce over the 16-lane l15 group (pixels), then lane l15==0 writes float4 per mi
        #pragma unroll
        for (int mi = 0; mi < 4; ++mi)
            #pragma unroll
            for (int r = 0; r < 4; ++r) {
                float a1 = s1v[mi][r], a2 = s2v[mi][r];
                #pragma unroll
                for (int d = 1; d < 16; d <<= 1) {
                    a1 += __shfl_xor(a1, d, 64);
                    a2 += __shfl_xor(a2, d, 64);
                }
                s1v[mi][r] = a1; s2v[mi][r] = a2;
            }
        if (l15 == 0) {
            #pragma unroll
            for (int mi = 0; mi < 4; ++mi) {
                const int o = wid*64 + 16*mi + l4*4;
                const float4 w1 = {s1v[mi][0], s1v[mi][1], s1v[mi][2], s1v[mi][3]};
                const float4 w2 = {s2v[mi][0], s2v[mi][1], s2v[mi][2], s2v[mi][3]};
                *(float4*)&hps[((size_t)b * 256 + pblk) * NC + o] = w1;
                *(float4*)&hpq[((size_t)b * 256 + pblk) * NC + o] = w2;
            }
        }
    } else {
        // acc: reg dim = px (16mi + l4*4 + r), lane dim = out (wid*64 + 16ni + l15)
        #pragma unroll
        for (int ni = 0; ni < 4; ++ni) {
            const int o = wid*64 + 16*ni + l15;
            const float bm = biasE[b*NC + o];
            float* colp = outF + ((size_t)b * NC + o) * HW + p0;
            #pragma unroll
            for (int mi = 0; mi < 4; ++mi) {
                const float4 v = {fmaxf(acc[mi][ni][0] + bm, 0.f),
                                  fmaxf(acc[mi][ni][1] + bm, 0.f),
                                  fmaxf(acc[mi][ni][2] + bm, 0.f),
                                  fmaxf(acc[mi][ni][3] + bm, 0.f)};
                *(float4*)&colp[16*mi + l4*4] = v;                  // 16B store, 4 consecutive px
            }
        }
    }
}

extern "C" void kernel_launch(void* const* d_in, const int* in_sizes, int n_in,
                              void* d_out, int out_size, void* d_ws, size_t ws_size,
                              hipStream_t stream)
{
    (void)in_sizes; (void)n_in; (void)out_size;
    const float* x  = (const float*)d_in[0];
    const float* w1 = (const float*)d_in[1];
    const float* b1 = (const float*)d_in[2];
    const float* w2 = (const float*)d_in[3];
    const float* b2 = (const float*)d_in[4];
    float* out = (float*)d_out;

    // scratch carved out of d_out (268 MB): dead before gemm<2> overwrites it
    char* od = (char*)d_out;
    u16*   xt  = (u16*)od;                        // 134,217,728 B
    float* xps = (float*)(od + 134217728);        //   4,194,304 (16*256*256 f32)
    float* xpq = (float*)(od + 138412032);        //   4,194,304
    float* hps = (float*)(od + 142606336);        //   4,194,304
    float* hpq = (float*)(od + 146800640);        //   4,194,304

    char* ws = (char*)d_ws;
    const size_t NEED = 138444800;
    if (ws_size < NEED) return;
    u16*   ht  = (u16*)(ws);                      // 134,217,728
    u16*   w1e = (u16*)(ws + 134217728);          //   2,097,152
    u16*   w2e = (u16*)(ws + 136314880);          //   2,097,152
    float* b1e = (float*)(ws + 138412032);        //      16,384
    float* b2e = (float*)(ws + 138428416);        //      16,384

    transpose_stats_kernel<<<dim3(HW/64, NC/64, 16), 256, 0, stream>>>(x, xt, xps, xpq);
    fold_kernel<<<dim3(4, 16), 256, 0, stream>>>(w1, b1, xps, xpq, w1e, b1e);
    gemm_kernel<1><<<dim3(HW/64, 16), 256, 0, stream>>>(xt, w1e, b1e, ht, nullptr, hps, hpq);
    fold_kernel<<<dim3(4, 16), 256, 0, stream>>>(w2, b2, hps, hpq, w2e, b2e);
    gemm_kernel<2><<<dim3(HW/64, 16), 256, 0, stream>>>(ht, w2e, b2e, nullptr, out, nullptr, nullptr);
}

// Round 10
// 321.633 us; speedup vs baseline: 1.2955x; 1.0504x over previous
//
#include <hip/hip_runtime.h>
#include <hip/hip_bf16.h>
#include <cstdint>
#include <cstddef>

#define DEVI __device__ __forceinline__

typedef unsigned short u16;
using frag_ab = __attribute__((ext_vector_type(8))) short;   // 8 bf16 (4 VGPRs)
using f32x4   = __attribute__((ext_vector_type(4))) float;   // mfma acc

constexpr int HW = 16384;   // 128*128 spatial
constexpr int NC = 256;     // channels (Cin = Cout = 256)

DEVI u16 bf16bits(float f) {
    union { float f; uint32_t u; } cv; cv.f = f;
    uint32_t u = cv.u;
    u += 0x7fffu + ((u >> 16) & 1u);   // RNE
    return (u16)(u >> 16);
}

DEVI void gload16(const void* g, void* l) {
    __builtin_amdgcn_global_load_lds(
        (const __attribute__((address_space(1))) uint32_t*)g,
        (__attribute__((address_space(3))) uint32_t*)l, 16, 0, 0);
}

// LDS slab: [row][64B]; 16B slot s at phys slot s ^ (row&3) ^ ((row>>2)&3).
// Staging fetches pre-swizzled global slot (m173); frag reads use matching phys.
DEVI frag_ab read_frag(const u16* slab, int row, int l4) {
    const int phys = (l4 ^ row ^ (row >> 2)) & 3;
    return *(const frag_ab*)((const char*)slab + row * 64 + phys * 16);
}

// ---------------- pass 1: x partial stats + transpose to xt[b][p][c] bf16 ----------------
// partials ps/pq[b][pblk][c]: full-sector float4 stores, fold reduces coalesced over pblk
__global__ __launch_bounds__(256) void transpose_stats_kernel(
    const float* __restrict__ x, u16* __restrict__ xt,
    float* __restrict__ ps, float* __restrict__ pq)
{
    constexpr int PADW = 68;                       // row pitch in u16 (136B)
    __shared__ __align__(16) u16 tile[64 * PADW];  // [px][ch]
    const int b = blockIdx.z, c0 = blockIdx.y * 64, p0 = blockIdx.x * 64;
    const int pblk = blockIdx.x;                   // 0..255
    const int t = threadIdx.x;
    const int lane = t & 63, w = t >> 6;
    const int pq_ = lane & 15, cq = lane >> 4;
    const int quad = w * 4 + cq;                   // ch-quad 0..15
    const float* xb = x + ((size_t)b * NC + c0) * HW + p0;

    float va[4][4];                                // [j=ch][i=px]
    float aS[4], aQ[4];
    #pragma unroll
    for (int j = 0; j < 4; ++j) {
        const float4 v = *(const float4*)(xb + (size_t)(quad * 4 + j) * HW + pq_ * 4);
        va[j][0] = v.x; va[j][1] = v.y; va[j][2] = v.z; va[j][3] = v.w;
        float s1 = v.x + v.y + v.z + v.w;
        float s2 = v.x*v.x + v.y*v.y + v.z*v.z + v.w*v.w;
        #pragma unroll
        for (int d = 1; d < 16; d <<= 1) {
            s1 += __shfl_xor(s1, d, 64);
            s2 += __shfl_xor(s2, d, 64);
        }
        aS[j] = s1; aQ[j] = s2;
    }
    if (pq_ == 0) {                                // lanes 0,16,32,48: one 16B store each
        const float4 vs = {aS[0], aS[1], aS[2], aS[3]};
        const float4 vq = {aQ[0], aQ[1], aQ[2], aQ[3]};
        *(float4*)&ps[((size_t)b * 256 + pblk) * NC + c0 + quad * 4] = vs;
        *(float4*)&pq[((size_t)b * 256 + pblk) * NC + c0 + quad * 4] = vq;
    }
    #pragma unroll
    for (int i = 0; i < 4; ++i) {
        alignas(8) u16 pk[4];
        #pragma unroll
        for (int j = 0; j < 4; ++j) pk[j] = bf16bits(va[j][i]);
        *(uint2*)&tile[(pq_ * 4 + i) * PADW + quad * 4] = *(const uint2*)pk;
    }
    __syncthreads();
    const int pl = t >> 2, q = t & 3;
    u16* dst = xt + ((size_t)b * HW + p0 + pl) * NC + c0;
    #pragma unroll
    for (int s = 0; s < 2; ++s) {
        const int ch8 = q + s * 4;
        const uint2 lo = *(const uint2*)&tile[pl * PADW + ch8 * 8];
        const uint2 hi = *(const uint2*)&tile[pl * PADW + ch8 * 8 + 4];
        const uint4 o4 = {lo.x, lo.y, hi.x, hi.y};
        *(uint4*)(dst + ch8 * 8) = o4;
    }
}

// ---------------- fold: reduce partials[b][256][c] -> mu/rs, fold IN into weights/bias ----------------
__global__ __launch_bounds__(256) void fold_kernel(
    const float* __restrict__ w, const float* __restrict__ bias,
    const float* __restrict__ ps, const float* __restrict__ pq,
    u16* __restrict__ we, float* __restrict__ be)
{
    const int b = blockIdx.y, oc = blockIdx.x * 64;
    __shared__ float mu[NC], rs[NC];
    __shared__ __align__(16) float wt[64 * NC];
    const int t = threadIdx.x;
    {
        float s1 = 0.f, s2 = 0.f;
        const float* pp = ps + (size_t)b * 256 * NC + t;    // [i][t], coalesced across threads
        const float* qq = pq + (size_t)b * 256 * NC + t;
        for (int i = 0; i < 256; ++i) {
            s1 += pp[(size_t)i * NC];
            s2 += qq[(size_t)i * NC];
        }
        const float m = s1 * (1.0f / HW);
        mu[t] = m;
        rs[t] = rsqrtf(s2 * (1.0f / HW) - m * m + 1e-5f);
    }
    #pragma unroll
    for (int i = 0; i < 16; ++i)
        *(float4*)&wt[i*1024 + t*4] = *(const float4*)&w[(size_t)oc*NC + i*1024 + t*4];
    __syncthreads();
    const int o = oc + (t >> 2), q = t & 3;
    const float* wrow = &wt[(t >> 2) * NC];
    u16* werow = we + ((size_t)b * NC + o) * NC;
    float bacc = 0.f;
    for (int cc = 0; cc < 8; ++cc) {
        alignas(16) u16 pk[8];
        #pragma unroll
        for (int jj = 0; jj < 8; ++jj) {
            const int c = q*64 + cc*8 + jj;
            const float wv = wrow[c];
            bacc -= wv * mu[c] * rs[c];
            pk[jj] = bf16bits(wv * rs[c]);
        }
        *(uint4*)(werow + q*64 + cc*8) = *(const uint4*)pk;
    }
    bacc += __shfl_xor(bacc, 1, 64);
    bacc += __shfl_xor(bacc, 2, 64);
    if (q == 0) be[b*NC + o] = bias[o] + bacc;
}

// ---------------- fused GEMM: multi-tile persistent pipeline, W in VGPRs ----------------
// Grid 512 blocks x 4 waves. Each block: batch b, 8 pixel tiles (pblk = blk + 32*i).
// Wave wid owns outs [wid*64, +64); its W quarter (64 x K=256) loaded ONCE into 128 VGPRs
// (wf[8][4], data-identical to the r9 LDS frags). Per tile: vmcnt(0)+barrier, issue next
// tile's 32 KB P strip (8 gload16), 8 k-steps x {4 ds_read_b128 + 16 MFMA} (no syncs),
// wide-store epilogue. Next strip's latency hides under MFMA+stores; load stream never stops.
// STAGE1 -> ht[b][p][o] bf16 + h partials [b][pblk][o]; STAGE2 -> out[b][o][p] fp32.
template<int STAGE>
__global__ __launch_bounds__(256, 2) void gemm_kernel(
    const u16* __restrict__ pixM,   // [B*HW][NC] (xt or ht)
    const u16* __restrict__ wMat,   // [B][NC][NC] folded weights
    const float* __restrict__ biasE,// [B][NC]
    u16* __restrict__ outB,         // stage1: ht
    float* __restrict__ outF,       // stage2: out
    float* __restrict__ hps, float* __restrict__ hpq)
{
    __shared__ __align__(16) u16 ldsP[2][16384];  // 2 strips: 64 px x 256 k bf16 (32 KB each)

    const int b   = blockIdx.x >> 5;              // 32 blocks per batch
    const int blk = blockIdx.x & 31;              // tile stride: pblk = blk + 32*i
    const int tid = threadIdx.x;
    const int lane = tid & 63, wid = tid >> 6;    // 4 waves; wave owns outs [wid*64, +64)
    const int l15 = lane & 15, l4 = lane >> 4;

    const u16* gW = wMat + (size_t)b * NC * NC;

    const int rin  = lane >> 2;
    const int prow = wid * 16 + rin;              // staged pixel row 0..63
    const int psl  = ((lane & 3) ^ prow ^ (prow >> 2)) & 3;

    auto stageP = [&](int i, int buf) {
        const u16* gPt = pixM + ((size_t)b * HW + (blk + 32 * i) * 64) * NC;
        #pragma unroll
        for (int ks = 0; ks < 8; ++ks)
            gload16(gPt + (size_t)prow * NC + ks * 32 + psl * 8,
                    (char*)ldsP[buf] + ks * 4096 + wid * 1024);
    };

    // ---- W quarter into VGPRs (one-time; rows wid*64+16f+l15, k = ks*32 + l4*8)
    frag_ab wf[8][4];
    {
        const u16* wb = gW + (size_t)(wid * 64 + l15) * NC + l4 * 8;
        #pragma unroll
        for (int ks = 0; ks < 8; ++ks)
            #pragma unroll
            for (int f = 0; f < 4; ++f)
                wf[ks][f] = *(const frag_ab*)(wb + (size_t)f * 16 * NC + ks * 32);
    }
    stageP(0, 0);

    for (int i = 0; i < 8; ++i) {
        asm volatile("s_waitcnt vmcnt(0)" ::: "memory");   // strip i (+ prior stores) drained
        __builtin_amdgcn_s_barrier();                      // all waves done reading buf (i&1)^1
        if (i < 7) stageP(i + 1, (i + 1) & 1);             // overlaps this tile's MFMA+stores

        f32x4 acc[4][4];
        #pragma unroll
        for (int mi = 0; mi < 4; ++mi)
            #pragma unroll
            for (int ni = 0; ni < 4; ++ni)
                acc[mi][ni] = (f32x4){0.f, 0.f, 0.f, 0.f};

        const u16* bufb = ldsP[i & 1];
        #pragma unroll
        for (int ks = 0; ks < 8; ++ks) {
            const u16* pslab = bufb + ks * 2048;           // 4096 B k-slice
            frag_ab pf[4];
            #pragma unroll
            for (int f = 0; f < 4; ++f)
                pf[f] = read_frag(pslab, 16 * f + l15, l4);
            #pragma unroll
            for (int ni = 0; ni < 4; ++ni)
                #pragma unroll
                for (int mi = 0; mi < 4; ++mi) {
                    if constexpr (STAGE == 1)   // A=W: acc reg dim = outs, lane dim = px
                        acc[mi][ni] = __builtin_amdgcn_mfma_f32_16x16x32_bf16(wf[ks][mi], pf[ni], acc[mi][ni], 0, 0, 0);
                    else                        // A=P: acc reg dim = px, lane dim = outs
                        acc[mi][ni] = __builtin_amdgcn_mfma_f32_16x16x32_bf16(pf[mi], wf[ks][ni], acc[mi][ni], 0, 0, 0);
                }
        }

        const int pblk = blk + 32 * i;
        const int p0 = pblk * 64;
        if constexpr (STAGE == 1) {
            // acc: reg dim = out (wid*64 + 16mi + l4*4 + r), lane dim = px (16ni + l15)
            u16* htbase = outB + ((size_t)b * HW + p0) * NC + wid * 64;
            #pragma unroll
            for (int mi = 0; mi < 4; ++mi) {
                const float4 vbm = *(const float4*)&biasE[b*NC + wid*64 + 16*mi + l4*4];
                const float bx[4] = {vbm.x, vbm.y, vbm.z, vbm.w};
                float s1r[4] = {0.f,0.f,0.f,0.f}, s2r[4] = {0.f,0.f,0.f,0.f};
                #pragma unroll
                for (int ni = 0; ni < 4; ++ni) {
                    u16* rowp = htbase + (size_t)(16*ni + l15) * NC;
                    alignas(8) u16 pk[4];
                    #pragma unroll
                    for (int r = 0; r < 4; ++r) {
                        const float v = fmaxf(acc[mi][ni][r] + bx[r], 0.f);
                        s1r[r] += v; s2r[r] += v * v;
                        pk[r] = bf16bits(v);
                    }
                    *(uint2*)&rowp[16*mi + l4*4] = *(const uint2*)pk;  // 8B: 4 consecutive o
                }
                #pragma unroll
                for (int r = 0; r < 4; ++r) {
                    float a1 = s1r[r], a2 = s2r[r];
                    #pragma unroll
                    for (int d = 1; d < 16; d <<= 1) {
                        a1 += __shfl_xor(a1, d, 64);
                        a2 += __shfl_xor(a2, d, 64);
                    }
                    s1r[r] = a1; s2r[r] = a2;
                }
                if (l15 == 0) {
                    const int o = wid*64 + 16*mi + l4*4;
                    const float4 w1v = {s1r[0], s1r[1], s1r[2], s1r[3]};
                    const float4 w2v = {s2r[0], s2r[1], s2r[2], s2r[3]};
                    *(float4*)&hps[((size_t)b * 256 + pblk) * NC + o] = w1v;
                    *(float4*)&hpq[((size_t)b * 256 + pblk) * NC + o] = w2v;
                }
            }
        } else {
            // acc: reg dim = px (16mi + l4*4 + r), lane dim = out (wid*64 + 16ni + l15)
            #pragma unroll
            for (int ni = 0; ni < 4; ++ni) {
                const int o = wid*64 + 16*ni + l15;
                const float bm = biasE[b*NC + o];
                float* colp = outF + ((size_t)b * NC + o) * HW + p0;
                #pragma unroll
                for (int mi = 0; mi < 4; ++mi) {
                    const float4 v = {fmaxf(acc[mi][ni][0] + bm, 0.f),
                                      fmaxf(acc[mi][ni][1] + bm, 0.f),
                                      fmaxf(acc[mi][ni][2] + bm, 0.f),
                                      fmaxf(acc[mi][ni][3] + bm, 0.f)};
                    *(float4*)&colp[16*mi + l4*4] = v;     // 16B: 4 consecutive px
                }
            }
        }
    }
}

extern "C" void kernel_launch(void* const* d_in, const int* in_sizes, int n_in,
                              void* d_out, int out_size, void* d_ws, size_t ws_size,
                              hipStream_t stream)
{
    (void)in_sizes; (void)n_in; (void)out_size;
    const float* x  = (const float*)d_in[0];
    const float* w1 = (const float*)d_in[1];
    const float* b1 = (const float*)d_in[2];
    const float* w2 = (const float*)d_in[3];
    const float* b2 = (const float*)d_in[4];
    float* out = (float*)d_out;

    // scratch carved out of d_out (268 MB): dead before gemm<2> overwrites it
    char* od = (char*)d_out;
    u16*   xt  = (u16*)od;                        // 134,217,728 B
    float* xps = (float*)(od + 134217728);        //   4,194,304 (16*256*256 f32)
    float* xpq = (float*)(od + 138412032);        //   4,194,304
    float* hps = (float*)(od + 142606336);        //   4,194,304
    float* hpq = (float*)(od + 146800640);        //   4,194,304

    char* ws = (char*)d_ws;
    const size_t NEED = 138444800;
    if (ws_size < NEED) return;
    u16*   ht  = (u16*)(ws);                      // 134,217,728
    u16*   w1e = (u16*)(ws + 134217728);          //   2,097,152
    u16*   w2e = (u16*)(ws + 136314880);          //   2,097,152
    float* b1e = (float*)(ws + 138412032);        //      16,384
    float* b2e = (float*)(ws + 138428416);        //      16,384

    transpose_stats_kernel<<<dim3(HW/64, NC/64, 16), 256, 0, stream>>>(x, xt, xps, xpq);
    fold_kernel<<<dim3(4, 16), 256, 0, stream>>>(w1, b1, xps, xpq, w1e, b1e);
    gemm_kernel<1><<<dim3(512), 256, 0, stream>>>(xt, w1e, b1e, ht, nullptr, hps, hpq);
    fold_kernel<<<dim3(4, 16), 256, 0, stream>>>(w2, b2, hps, hpq, w2e, b2e);
    gemm_kernel<2><<<dim3(512), 256, 0, stream>>>(ht, w2e, b2e, nullptr, out, nullptr, nullptr);
}